// Round 2
// baseline (308.105 us; speedup 1.0000x reference)
//
#include <hip/hip_runtime.h>
#include <hip/hip_bf16.h>
#include <stdint.h>

typedef __bf16 bf16;
typedef __bf16 bf16x8 __attribute__((ext_vector_type(8)));
typedef float f32x4 __attribute__((ext_vector_type(4)));

#define B_ 2
#define S_ 2048
#define D_ 1024
#define H_ 16
#define DK 64
#define M_ 4096

__device__ __forceinline__ void gload_lds16(const void* g, void* l) {
  __builtin_amdgcn_global_load_lds(
      (const __attribute__((address_space(1))) uint32_t*)(uintptr_t)g,
      (__attribute__((address_space(3))) uint32_t*)(uintptr_t)l, 16, 0, 0);
}

// ---------------- f32 -> bf16 convert ----------------
struct alignas(8) B4s { bf16 a, b, c, d; };

__global__ __launch_bounds__(256) void cvt_bf16_kernel(const float* __restrict__ in,
                                                       bf16* __restrict__ out, int n4) {
  int i = blockIdx.x * 256 + threadIdx.x;
  if (i < n4) {
    float4 v = reinterpret_cast<const float4*>(in)[i];
    B4s o{(bf16)v.x, (bf16)v.y, (bf16)v.z, (bf16)v.w};
    reinterpret_cast<B4s*>(out)[i] = o;
  }
}

// ---------------- GEMM: C[m][n] = sum_k A[m][k] * W[n][k] ----------------
// MODE 0: A = xb [4096][1024], N = 3072 across Wq/Wk/Wv, out -> Q/K/V head-major bf16
// MODE 1: A = Ob [4096][1024], W = Wo, out -> f32 d_out [4096][1024]
template <int MODE>
__global__ __launch_bounds__(256) void gemm_kernel(
    const bf16* __restrict__ A,
    const bf16* __restrict__ W0, const bf16* __restrict__ W1, const bf16* __restrict__ W2,
    bf16* __restrict__ q_out, bf16* __restrict__ k_out, bf16* __restrict__ v_out,
    float* __restrict__ c_out) {
  constexpr int BK = 32;
  __shared__ bf16 Alds[128 * BK];
  __shared__ bf16 Blds[128 * BK];
  const int tid = threadIdx.x;
  const int w = tid >> 6, l = tid & 63;
  const int lr = l & 15, lg = l >> 4;
  const int m0 = blockIdx.y * 128;
  const int nt = blockIdx.x;
  const bf16* W;
  int n0;
  if (MODE == 0) {
    W = (nt >> 3) == 0 ? W0 : ((nt >> 3) == 1 ? W1 : W2);
    n0 = (nt & 7) * 128;
  } else {
    W = W0;
    n0 = nt * 128;
  }
  const int K = 1024;
  const int wm = (w >> 1) * 64, wn = (w & 1) * 64;
  const int srow = w * 16 + (l >> 2);  // staging row (second instr adds 64)
  const int scol = (l & 3) * 8;
  f32x4 acc[4][4] = {};
  for (int k0 = 0; k0 < K; k0 += BK) {
    gload_lds16(A + (size_t)(m0 + srow) * K + k0 + scol, Alds + (w * 16) * BK);
    gload_lds16(A + (size_t)(m0 + 64 + srow) * K + k0 + scol, Alds + (64 + w * 16) * BK);
    gload_lds16(W + (size_t)(n0 + srow) * K + k0 + scol, Blds + (w * 16) * BK);
    gload_lds16(W + (size_t)(n0 + 64 + srow) * K + k0 + scol, Blds + (64 + w * 16) * BK);
    __syncthreads();
    bf16x8 af[4], bfr[4];
#pragma unroll
    for (int f = 0; f < 4; ++f) {
      af[f]  = *reinterpret_cast<const bf16x8*>(Alds + (wm + f * 16 + lr) * BK + lg * 8);
      bfr[f] = *reinterpret_cast<const bf16x8*>(Blds + (wn + f * 16 + lr) * BK + lg * 8);
    }
#pragma unroll
    for (int fm = 0; fm < 4; ++fm)
#pragma unroll
      for (int fn = 0; fn < 4; ++fn)
        acc[fm][fn] = __builtin_amdgcn_mfma_f32_16x16x32_bf16(af[fm], bfr[fn], acc[fm][fn], 0, 0, 0);
    __syncthreads();
  }
#pragma unroll
  for (int fm = 0; fm < 4; ++fm)
#pragma unroll
    for (int fn = 0; fn < 4; ++fn)
#pragma unroll
      for (int r = 0; r < 4; ++r) {
        int m = m0 + wm + fm * 16 + lg * 4 + r;
        int n = n0 + wn + fn * 16 + lr;
        float v = acc[fm][fn][r];
        if (MODE == 0) {
          bf16* dst = (nt >> 3) == 0 ? q_out : ((nt >> 3) == 1 ? k_out : v_out);
          int h = n >> 6, d = n & 63;
          int b = m >> 11, s = m & 2047;
          dst[(((size_t)b * H_ + h) * S_ + s) * DK + d] = (bf16)v;
        } else {
          c_out[(size_t)m * D_ + n] = v;
        }
      }
}

// ---------------- RoPE (in-place on Q and K, head-major [32][2048][64]) ----------------
__global__ __launch_bounds__(256) void rope_kernel(bf16* __restrict__ Q, bf16* __restrict__ K) {
  const size_t NP = (size_t)32 * 2048 * 32;  // pairs per tensor
  size_t idx = (size_t)blockIdx.x * 256 + threadIdx.x;
  bf16* X = Q;
  if (idx >= NP) { X = K; idx -= NP; }
  int i = (int)(idx & 31);
  int s = (int)((idx >> 5) & 2047);
  int bh = (int)(idx >> 16);
  size_t off = ((size_t)bh * S_ + s) * DK + 2 * i;
  float ang = (float)s * powf(10000.0f, -(float)(2 * i) * (1.0f / 64.0f));
  float sn, cs;
  sincosf(ang, &sn, &cs);
  float x1 = (float)X[off], x2 = (float)X[off + 1];
  X[off]     = (bf16)(x1 * cs - x2 * sn);
  X[off + 1] = (bf16)(x1 * sn + x2 * cs);
}

// ---------------- causal flash attention ----------------
// grid: (32 q-tiles, 32 bh). block 256 = 4 waves, each wave owns 16 q rows.
// swapped QK^T: s = mfma(K_frag, Q_frag) -> lane holds scores for q = lr, keys = kf*16+4*lg+r
// PV: V staged TRANSPOSED in LDS (Vt[d][key ^ ((d&7)*8)]) so B-fragments are plain
// ds_read_b128 (T2 XOR swizzle keeps 8-element contiguity: XOR bits are >= bit 3).
__global__ __launch_bounds__(256) void attn_kernel(
    const bf16* __restrict__ Q, const bf16* __restrict__ K, const bf16* __restrict__ V,
    bf16* __restrict__ O) {
  __shared__ bf16 Vt[64 * 64];         // [d][key ^ ((d&7)*8)]
  __shared__ bf16 Plds[4][16 * 72];    // per-wave [16 q][64+8 keys]
  const int tid = threadIdx.x;
  const int w = tid >> 6, l = tid & 63;
  const int lr = l & 15, lg = l >> 4;
  const int bh = blockIdx.y;
  const int q0 = blockIdx.x * 64;
  const size_t base = (size_t)bh * S_ * DK;
  const int myq = q0 + w * 16 + lr;

  bf16x8 qf[2];
  qf[0] = *reinterpret_cast<const bf16x8*>(Q + base + (size_t)myq * DK + lg * 8);
  qf[1] = *reinterpret_cast<const bf16x8*>(Q + base + (size_t)myq * DK + 32 + lg * 8);

  float m_run = -INFINITY, l_run = 0.f;
  f32x4 o_acc[4] = {};
  bf16* Pw = Plds[w];

  const int nkt = blockIdx.x + 1;
  for (int kt = 0; kt < nkt; ++kt) {
    __syncthreads();
    // stage V^T: thread reads 8 contiguous d of one key, scatters to Vt rows
#pragma unroll
    for (int i = 0; i < 2; ++i) {
      int key = i * 32 + (tid >> 3);
      int d0 = (tid & 7) * 8;
      bf16x8 vv = *reinterpret_cast<const bf16x8*>(V + base + (size_t)(kt * 64 + key) * DK + d0);
#pragma unroll
      for (int j = 0; j < 8; ++j)
        Vt[(d0 + j) * 64 + (key ^ (j * 8))] = vv[j];  // (d&7)==j since d0%8==0
    }
    __syncthreads();

    f32x4 s[4];
#pragma unroll
    for (int kf = 0; kf < 4; ++kf) {
      f32x4 a = {};
#pragma unroll
      for (int kk = 0; kk < 2; ++kk) {
        bf16x8 kfr = *reinterpret_cast<const bf16x8*>(
            K + base + (size_t)(kt * 64 + kf * 16 + lr) * DK + kk * 32 + lg * 8);
        a = __builtin_amdgcn_mfma_f32_16x16x32_bf16(kfr, qf[kk], a, 0, 0, 0);
      }
      s[kf] = a;
    }
    float tmax = -INFINITY;
    const bool lastt = (kt == nkt - 1);
#pragma unroll
    for (int kf = 0; kf < 4; ++kf)
#pragma unroll
      for (int r = 0; r < 4; ++r) {
        float v = s[kf][r] * 0.125f;
        if (lastt) {
          int key = kt * 64 + kf * 16 + 4 * lg + r;
          if (key > myq) v = -INFINITY;
        }
        s[kf][r] = v;
        tmax = fmaxf(tmax, v);
      }
    tmax = fmaxf(tmax, __shfl_xor(tmax, 16));
    tmax = fmaxf(tmax, __shfl_xor(tmax, 32));
    float m_new = fmaxf(m_run, tmax);
    float sf = __expf(m_run - m_new);
    float ts = 0.f;
#pragma unroll
    for (int kf = 0; kf < 4; ++kf)
#pragma unroll
      for (int r = 0; r < 4; ++r) {
        float p = __expf(s[kf][r] - m_new);
        s[kf][r] = p;
        ts += p;
      }
    ts += __shfl_xor(ts, 16);
    ts += __shfl_xor(ts, 32);
    l_run = l_run * sf + ts;
    m_run = m_new;

#pragma unroll
    for (int kf = 0; kf < 4; ++kf) {
      B4s p4{(bf16)s[kf][0], (bf16)s[kf][1], (bf16)s[kf][2], (bf16)s[kf][3]};
      *reinterpret_cast<B4s*>(Pw + lr * 72 + kf * 16 + 4 * lg) = p4;
    }
    float sfr0 = __shfl(sf, 4 * lg + 0);
    float sfr1 = __shfl(sf, 4 * lg + 1);
    float sfr2 = __shfl(sf, 4 * lg + 2);
    float sfr3 = __shfl(sf, 4 * lg + 3);
#pragma unroll
    for (int dt = 0; dt < 4; ++dt) {
      o_acc[dt][0] *= sfr0; o_acc[dt][1] *= sfr1;
      o_acc[dt][2] *= sfr2; o_acc[dt][3] *= sfr3;
    }
    bf16x8 pa[2];
    pa[0] = *reinterpret_cast<const bf16x8*>(Pw + lr * 72 + lg * 8);
    pa[1] = *reinterpret_cast<const bf16x8*>(Pw + lr * 72 + 32 + lg * 8);
#pragma unroll
    for (int dt = 0; dt < 4; ++dt) {
      int d = dt * 16 + lr;
      const int sw = (d & 7) * 8;
      bf16x8 v0 = *reinterpret_cast<const bf16x8*>(Vt + d * 64 + ((lg * 8) ^ sw));
      bf16x8 v1 = *reinterpret_cast<const bf16x8*>(Vt + d * 64 + ((32 + lg * 8) ^ sw));
      o_acc[dt] = __builtin_amdgcn_mfma_f32_16x16x32_bf16(pa[0], v0, o_acc[dt], 0, 0, 0);
      o_acc[dt] = __builtin_amdgcn_mfma_f32_16x16x32_bf16(pa[1], v1, o_acc[dt], 0, 0, 0);
    }
  }
  float inv = 1.0f / l_run;
  float ir[4];
  ir[0] = __shfl(inv, 4 * lg + 0);
  ir[1] = __shfl(inv, 4 * lg + 1);
  ir[2] = __shfl(inv, 4 * lg + 2);
  ir[3] = __shfl(inv, 4 * lg + 3);
  int b = bh >> 4, h = bh & 15;
#pragma unroll
  for (int dt = 0; dt < 4; ++dt)
#pragma unroll
    for (int r = 0; r < 4; ++r) {
      int qrow = q0 + w * 16 + 4 * lg + r;
      int n = h * DK + dt * 16 + lr;
      O[((size_t)b * S_ + qrow) * D_ + n] = (bf16)(o_acc[dt][r] * ir[r]);
    }
}

extern "C" void kernel_launch(void* const* d_in, const int* in_sizes, int n_in,
                              void* d_out, int out_size, void* d_ws, size_t ws_size,
                              hipStream_t stream) {
  const float* x  = (const float*)d_in[0];
  const float* Wq = (const float*)d_in[1];
  const float* Wk = (const float*)d_in[2];
  const float* Wv = (const float*)d_in[3];
  const float* Wo = (const float*)d_in[4];
  float* out = (float*)d_out;
  char* ws = (char*)d_ws;

  bf16* xb  = (bf16*)(ws + ((size_t)0 << 20));
  bf16* wqb = (bf16*)(ws + ((size_t)8 << 20));
  bf16* wkb = (bf16*)(ws + ((size_t)10 << 20));
  bf16* wvb = (bf16*)(ws + ((size_t)12 << 20));
  bf16* wob = (bf16*)(ws + ((size_t)14 << 20));
  bf16* Qb  = (bf16*)(ws + ((size_t)16 << 20));
  bf16* Kb  = (bf16*)(ws + ((size_t)24 << 20));
  bf16* Vb  = (bf16*)(ws + ((size_t)32 << 20));
  bf16* Ob  = (bf16*)(ws + ((size_t)40 << 20));

  cvt_bf16_kernel<<<4096, 256, 0, stream>>>(x, xb, 1048576);
  cvt_bf16_kernel<<<1024, 256, 0, stream>>>(Wq, wqb, 262144);
  cvt_bf16_kernel<<<1024, 256, 0, stream>>>(Wk, wkb, 262144);
  cvt_bf16_kernel<<<1024, 256, 0, stream>>>(Wv, wvb, 262144);
  cvt_bf16_kernel<<<1024, 256, 0, stream>>>(Wo, wob, 262144);

  gemm_kernel<0><<<dim3(24, 32), 256, 0, stream>>>(xb, wqb, wkb, wvb, Qb, Kb, Vb, nullptr);
  rope_kernel<<<16384, 256, 0, stream>>>(Qb, Kb);
  attn_kernel<<<dim3(32, 32), 256, 0, stream>>>(Qb, Kb, Vb, Ob);
  gemm_kernel<1><<<dim3(8, 32), 256, 0, stream>>>(Ob, wob, nullptr, nullptr, nullptr, nullptr,
                                                  nullptr, out);
}

// Round 3
// 144.246 us; speedup vs baseline: 2.1360x; 2.1360x over previous
//
#include <hip/hip_runtime.h>
#include <hip/hip_bf16.h>
#include <stdint.h>

typedef __bf16 bf16;
typedef __bf16 bf16x8 __attribute__((ext_vector_type(8)));
typedef float f32x4 __attribute__((ext_vector_type(4)));

#define B_ 2
#define S_ 2048
#define D_ 1024
#define H_ 16
#define DK 64
#define M_ 4096

__device__ __forceinline__ void gload_lds16(const void* g, void* l) {
  __builtin_amdgcn_global_load_lds(
      (const __attribute__((address_space(1))) uint32_t*)(uintptr_t)g,
      (__attribute__((address_space(3))) uint32_t*)(uintptr_t)l, 16, 0, 0);
}

// ---------------- f32 -> bf16 convert ----------------
struct alignas(8) B4s { bf16 a, b, c, d; };

__global__ __launch_bounds__(256) void cvt_bf16_kernel(const float* __restrict__ in,
                                                       bf16* __restrict__ out, int n4) {
  int i = blockIdx.x * 256 + threadIdx.x;
  if (i < n4) {
    float4 v = reinterpret_cast<const float4*>(in)[i];
    B4s o{(bf16)v.x, (bf16)v.y, (bf16)v.z, (bf16)v.w};
    reinterpret_cast<B4s*>(out)[i] = o;
  }
}

// ---------------- GEMM: C[m][n] = sum_k A[m][k] * W[n][k] ----------------
template <int MODE>
__global__ __launch_bounds__(256) void gemm_kernel(
    const bf16* __restrict__ A,
    const bf16* __restrict__ W0, const bf16* __restrict__ W1, const bf16* __restrict__ W2,
    bf16* __restrict__ q_out, bf16* __restrict__ k_out, bf16* __restrict__ v_out,
    float* __restrict__ c_out) {
  constexpr int BK = 32;
  __shared__ bf16 Alds[128 * BK];
  __shared__ bf16 Blds[128 * BK];
  const int tid = threadIdx.x;
  const int w = tid >> 6, l = tid & 63;
  const int lr = l & 15, lg = l >> 4;
  const int m0 = blockIdx.y * 128;
  const int nt = blockIdx.x;
  const bf16* W;
  int n0;
  if (MODE == 0) {
    W = (nt >> 3) == 0 ? W0 : ((nt >> 3) == 1 ? W1 : W2);
    n0 = (nt & 7) * 128;
  } else {
    W = W0;
    n0 = nt * 128;
  }
  const int K = 1024;
  const int wm = (w >> 1) * 64, wn = (w & 1) * 64;
  const int srow = w * 16 + (l >> 2);
  const int scol = (l & 3) * 8;
  f32x4 acc[4][4] = {};
  for (int k0 = 0; k0 < K; k0 += BK) {
    gload_lds16(A + (size_t)(m0 + srow) * K + k0 + scol, Alds + (w * 16) * BK);
    gload_lds16(A + (size_t)(m0 + 64 + srow) * K + k0 + scol, Alds + (64 + w * 16) * BK);
    gload_lds16(W + (size_t)(n0 + srow) * K + k0 + scol, Blds + (w * 16) * BK);
    gload_lds16(W + (size_t)(n0 + 64 + srow) * K + k0 + scol, Blds + (64 + w * 16) * BK);
    __syncthreads();
    bf16x8 af[4], bfr[4];
#pragma unroll
    for (int f = 0; f < 4; ++f) {
      af[f]  = *reinterpret_cast<const bf16x8*>(Alds + (wm + f * 16 + lr) * BK + lg * 8);
      bfr[f] = *reinterpret_cast<const bf16x8*>(Blds + (wn + f * 16 + lr) * BK + lg * 8);
    }
#pragma unroll
    for (int fm = 0; fm < 4; ++fm)
#pragma unroll
      for (int fn = 0; fn < 4; ++fn)
        acc[fm][fn] = __builtin_amdgcn_mfma_f32_16x16x32_bf16(af[fm], bfr[fn], acc[fm][fn], 0, 0, 0);
    __syncthreads();
  }
#pragma unroll
  for (int fm = 0; fm < 4; ++fm)
#pragma unroll
    for (int fn = 0; fn < 4; ++fn)
#pragma unroll
      for (int r = 0; r < 4; ++r) {
        int m = m0 + wm + fm * 16 + lg * 4 + r;
        int n = n0 + wn + fn * 16 + lr;
        float v = acc[fm][fn][r];
        if (MODE == 0) {
          bf16* dst = (nt >> 3) == 0 ? q_out : ((nt >> 3) == 1 ? k_out : v_out);
          int h = n >> 6, d = n & 63;
          int b = m >> 11, s = m & 2047;
          dst[(((size_t)b * H_ + h) * S_ + s) * DK + d] = (bf16)v;
        } else {
          c_out[(size_t)m * D_ + n] = v;
        }
      }
}

// ---------------- RoPE (vectorized, fast-math) ----------------
__global__ __launch_bounds__(256) void rope_kernel(bf16* __restrict__ Q, bf16* __restrict__ K) {
  const int NG = 32 * 2048 * 8;  // bf16x8 groups per tensor
  int idx = blockIdx.x * 256 + threadIdx.x;
  bf16* X = Q;
  if (idx >= NG) { X = K; idx -= NG; }
  int g = idx & 7;
  int s = (idx >> 3) & 2047;
  int bh = idx >> 14;
  size_t off = ((size_t)bh * S_ + s) * DK + g * 8;
  bf16x8 v = *reinterpret_cast<const bf16x8*>(X + off);
  bf16x8 o;
  const float c0 = -0.4152410118609203f;  // -log2(10000)/32
  float fs = (float)s;
#pragma unroll
  for (int p = 0; p < 4; ++p) {
    int i = g * 4 + p;
    float ang = fs * exp2f((float)i * c0);
    float sn = __sinf(ang), cs = __cosf(ang);
    float x1 = (float)v[2 * p], x2 = (float)v[2 * p + 1];
    o[2 * p]     = (bf16)(x1 * cs - x2 * sn);
    o[2 * p + 1] = (bf16)(x1 * sn + x2 * cs);
  }
  *reinterpret_cast<bf16x8*>(X + off) = o;
}

// ---------------- causal flash attention (paired q-tiles, balanced) ----------------
// grid (16, 32): block i handles q-tiles lo=i and hi=31-i of bh=blockIdx.y.
// 4 waves; each wave owns 16 q rows of each tile. KVBLK=64.
// K staged in LDS via pre-swizzled global_load_lds (XOR (row&7)*8 elements).
// V staged transposed (Vt[d][key ^ ((d&7)*8)]) with per-wave distinct keys (2-way writes).
__global__ __launch_bounds__(256) void attn_kernel(
    const bf16* __restrict__ Q, const bf16* __restrict__ K, const bf16* __restrict__ V,
    bf16* __restrict__ O) {
  __shared__ bf16 Klds[64 * 64];
  __shared__ bf16 Vt[64 * 64];
  __shared__ bf16 Plds[8][16 * 72];
  const int tid = threadIdx.x;
  const int w = tid >> 6, l = tid & 63;
  const int lr = l & 15, lg = l >> 4;
  const int bh = blockIdx.y;
  const int lo = blockIdx.x, hi = 31 - blockIdx.x;
  const size_t base = (size_t)bh * S_ * DK;

  bf16x8 qfl[2], qfh[2];
  {
    const size_t rl = base + (size_t)(lo * 64 + w * 16 + lr) * DK;
    const size_t rh = base + (size_t)(hi * 64 + w * 16 + lr) * DK;
    qfl[0] = *reinterpret_cast<const bf16x8*>(Q + rl + lg * 8);
    qfl[1] = *reinterpret_cast<const bf16x8*>(Q + rl + 32 + lg * 8);
    qfh[0] = *reinterpret_cast<const bf16x8*>(Q + rh + lg * 8);
    qfh[1] = *reinterpret_cast<const bf16x8*>(Q + rh + 32 + lg * 8);
  }

  float m_lo = -INFINITY, l_lo = 0.f, m_hi = -INFINITY, l_hi = 0.f;
  f32x4 o_lo[4] = {}, o_hi[4] = {};

  // K staging geometry: call c covers rows c*8..c*8+7; lane l -> row c*8+(l>>3),
  // src col = ((l&7)*8) ^ ((row&7)*8)  (pre-swizzled so LDS holds swizzled image)
  const int ksr = l >> 3;
  const int ksc = (l & 7) * 8;

  auto process = [&](const bf16x8 (&qf)[2], const bf16x8 (&kfr)[4][2],
                     const bf16x8 (&vfr)[4][2], float& m_run, float& l_run,
                     f32x4 (&o_acc)[4], bf16* Pw, bool lastt) {
    f32x4 s[4];
#pragma unroll
    for (int kf = 0; kf < 4; ++kf) {
      f32x4 a = {};
      a = __builtin_amdgcn_mfma_f32_16x16x32_bf16(kfr[kf][0], qf[0], a, 0, 0, 0);
      a = __builtin_amdgcn_mfma_f32_16x16x32_bf16(kfr[kf][1], qf[1], a, 0, 0, 0);
      s[kf] = a;
    }
    float tmax = -INFINITY;
#pragma unroll
    for (int kf = 0; kf < 4; ++kf)
#pragma unroll
      for (int r = 0; r < 4; ++r) {
        float v = s[kf][r] * 0.125f;
        if (lastt) {
          if (kf * 16 + 4 * lg + r > w * 16 + lr) v = -INFINITY;
        }
        s[kf][r] = v;
        tmax = fmaxf(tmax, v);
      }
    tmax = fmaxf(tmax, __shfl_xor(tmax, 16));
    tmax = fmaxf(tmax, __shfl_xor(tmax, 32));
    float m_new = fmaxf(m_run, tmax);
    float sf = __expf(m_run - m_new);
    float ts = 0.f;
#pragma unroll
    for (int kf = 0; kf < 4; ++kf)
#pragma unroll
      for (int r = 0; r < 4; ++r) {
        float p = __expf(s[kf][r] - m_new);
        s[kf][r] = p;
        ts += p;
      }
    ts += __shfl_xor(ts, 16);
    ts += __shfl_xor(ts, 32);
    l_run = l_run * sf + ts;
    m_run = m_new;
#pragma unroll
    for (int kf = 0; kf < 4; ++kf) {
      B4s p4{(bf16)s[kf][0], (bf16)s[kf][1], (bf16)s[kf][2], (bf16)s[kf][3]};
      *reinterpret_cast<B4s*>(Pw + lr * 72 + kf * 16 + 4 * lg) = p4;
    }
    float sfr0 = __shfl(sf, 4 * lg + 0);
    float sfr1 = __shfl(sf, 4 * lg + 1);
    float sfr2 = __shfl(sf, 4 * lg + 2);
    float sfr3 = __shfl(sf, 4 * lg + 3);
#pragma unroll
    for (int dt = 0; dt < 4; ++dt) {
      o_acc[dt][0] *= sfr0; o_acc[dt][1] *= sfr1;
      o_acc[dt][2] *= sfr2; o_acc[dt][3] *= sfr3;
    }
    bf16x8 pa0 = *reinterpret_cast<const bf16x8*>(Pw + lr * 72 + lg * 8);
    bf16x8 pa1 = *reinterpret_cast<const bf16x8*>(Pw + lr * 72 + 32 + lg * 8);
#pragma unroll
    for (int dt = 0; dt < 4; ++dt) {
      o_acc[dt] = __builtin_amdgcn_mfma_f32_16x16x32_bf16(pa0, vfr[dt][0], o_acc[dt], 0, 0, 0);
      o_acc[dt] = __builtin_amdgcn_mfma_f32_16x16x32_bf16(pa1, vfr[dt][1], o_acc[dt], 0, 0, 0);
    }
  };

  for (int kt = 0; kt <= hi; ++kt) {
    __syncthreads();
    // --- stage K (global_load_lds, pre-swizzled source) ---
#pragma unroll
    for (int c2 = 0; c2 < 2; ++c2) {
      int c = w * 2 + c2;
      int row = c * 8 + ksr;
      gload_lds16(K + base + (size_t)(kt * 64 + row) * DK + (ksc ^ ((row & 7) * 8)),
                  Klds + c * 512);
    }
    // --- stage V^T (reg path; per-wave lanes cover 64 distinct keys) ---
    {
      bf16x8 vv0 = *reinterpret_cast<const bf16x8*>(V + base + (size_t)(kt * 64 + l) * DK + w * 8);
      bf16x8 vv1 = *reinterpret_cast<const bf16x8*>(V + base + (size_t)(kt * 64 + l) * DK + w * 8 + 32);
#pragma unroll
      for (int j = 0; j < 8; ++j) {
        Vt[(w * 8 + j) * 64 + (l ^ (j * 8))] = vv0[j];
        Vt[(w * 8 + 32 + j) * 64 + (l ^ (j * 8))] = vv1[j];
      }
    }
    __syncthreads();

    // --- preload K/V fragments (shared by both tiles) ---
    bf16x8 kfr[4][2], vfr[4][2];
#pragma unroll
    for (int kf = 0; kf < 4; ++kf) {
      int key = kf * 16 + lr;
#pragma unroll
      for (int kk = 0; kk < 2; ++kk)
        kfr[kf][kk] = *reinterpret_cast<const bf16x8*>(
            Klds + key * 64 + ((kk * 32 + lg * 8) ^ ((key & 7) * 8)));
    }
#pragma unroll
    for (int dt = 0; dt < 4; ++dt) {
      int d = dt * 16 + lr;
      int sw = (d & 7) * 8;
      vfr[dt][0] = *reinterpret_cast<const bf16x8*>(Vt + d * 64 + ((lg * 8) ^ sw));
      vfr[dt][1] = *reinterpret_cast<const bf16x8*>(Vt + d * 64 + ((32 + lg * 8) ^ sw));
    }

    process(qfh, kfr, vfr, m_hi, l_hi, o_hi, Plds[w], kt == hi);
    if (kt <= lo)
      process(qfl, kfr, vfr, m_lo, l_lo, o_lo, Plds[w + 4], kt == lo);
  }

  const int b = bh >> 4, h = bh & 15;
  auto epi = [&](float l_run, f32x4 (&o_acc)[4], int q0t) {
    float inv = 1.0f / l_run;
    float ir[4];
    ir[0] = __shfl(inv, 4 * lg + 0);
    ir[1] = __shfl(inv, 4 * lg + 1);
    ir[2] = __shfl(inv, 4 * lg + 2);
    ir[3] = __shfl(inv, 4 * lg + 3);
#pragma unroll
    for (int dt = 0; dt < 4; ++dt)
#pragma unroll
      for (int r = 0; r < 4; ++r) {
        int qrow = q0t + w * 16 + 4 * lg + r;
        int n = h * DK + dt * 16 + lr;
        O[((size_t)b * S_ + qrow) * D_ + n] = (bf16)(o_acc[dt][r] * ir[r]);
      }
  };
  epi(l_hi, o_hi, hi * 64);
  epi(l_lo, o_lo, lo * 64);
}

extern "C" void kernel_launch(void* const* d_in, const int* in_sizes, int n_in,
                              void* d_out, int out_size, void* d_ws, size_t ws_size,
                              hipStream_t stream) {
  const float* x  = (const float*)d_in[0];
  const float* Wq = (const float*)d_in[1];
  const float* Wk = (const float*)d_in[2];
  const float* Wv = (const float*)d_in[3];
  const float* Wo = (const float*)d_in[4];
  float* out = (float*)d_out;
  char* ws = (char*)d_ws;

  bf16* xb  = (bf16*)(ws + ((size_t)0 << 20));
  bf16* wqb = (bf16*)(ws + ((size_t)8 << 20));
  bf16* wkb = (bf16*)(ws + ((size_t)10 << 20));
  bf16* wvb = (bf16*)(ws + ((size_t)12 << 20));
  bf16* wob = (bf16*)(ws + ((size_t)14 << 20));
  bf16* Qb  = (bf16*)(ws + ((size_t)16 << 20));
  bf16* Kb  = (bf16*)(ws + ((size_t)24 << 20));
  bf16* Vb  = (bf16*)(ws + ((size_t)32 << 20));
  bf16* Ob  = (bf16*)(ws + ((size_t)40 << 20));

  cvt_bf16_kernel<<<4096, 256, 0, stream>>>(x, xb, 1048576);
  cvt_bf16_kernel<<<1024, 256, 0, stream>>>(Wq, wqb, 262144);
  cvt_bf16_kernel<<<1024, 256, 0, stream>>>(Wk, wkb, 262144);
  cvt_bf16_kernel<<<1024, 256, 0, stream>>>(Wv, wvb, 262144);
  cvt_bf16_kernel<<<1024, 256, 0, stream>>>(Wo, wob, 262144);

  gemm_kernel<0><<<dim3(24, 32), 256, 0, stream>>>(xb, wqb, wkb, wvb, Qb, Kb, Vb, nullptr);
  rope_kernel<<<4096, 256, 0, stream>>>(Qb, Kb);
  attn_kernel<<<dim3(16, 32), 256, 0, stream>>>(Qb, Kb, Vb, Ob);
  gemm_kernel<1><<<dim3(8, 32), 256, 0, stream>>>(Ob, wob, nullptr, nullptr, nullptr, nullptr,
                                                  nullptr, out);
}

// Round 4
// 134.110 us; speedup vs baseline: 2.2974x; 1.0756x over previous
//
#include <hip/hip_runtime.h>
#include <hip/hip_bf16.h>
#include <stdint.h>

typedef __bf16 bf16;
typedef __bf16 bf16x8 __attribute__((ext_vector_type(8)));
typedef float f32x4 __attribute__((ext_vector_type(4)));

#define B_ 2
#define S_ 2048
#define D_ 1024
#define H_ 16
#define DK 64
#define M_ 4096

__device__ __forceinline__ void gload_lds16(const void* g, void* l) {
  __builtin_amdgcn_global_load_lds(
      (const __attribute__((address_space(1))) uint32_t*)(uintptr_t)g,
      (__attribute__((address_space(3))) uint32_t*)(uintptr_t)l, 16, 0, 0);
}

// ---------------- f32 -> bf16 convert (all 5 tensors, one launch) ----------------
struct alignas(8) B4s { bf16 a, b, c, d; };

__global__ __launch_bounds__(256) void cvt_all_kernel(
    const float* __restrict__ x, const float* __restrict__ wq, const float* __restrict__ wk,
    const float* __restrict__ wv, const float* __restrict__ wo,
    bf16* __restrict__ xb, bf16* __restrict__ wqb, bf16* __restrict__ wkb,
    bf16* __restrict__ wvb, bf16* __restrict__ wob) {
  int i = blockIdx.x * 256 + threadIdx.x;  // float4 index
  const float* src;
  bf16* dst;
  int off;
  if (i < 1048576) { src = x; dst = xb; off = i; }
  else if (i < 1310720) { src = wq; dst = wqb; off = i - 1048576; }
  else if (i < 1572864) { src = wk; dst = wkb; off = i - 1310720; }
  else if (i < 1835008) { src = wv; dst = wvb; off = i - 1572864; }
  else { src = wo; dst = wob; off = i - 1835008; }
  float4 v = reinterpret_cast<const float4*>(src)[off];
  B4s o{(bf16)v.x, (bf16)v.y, (bf16)v.z, (bf16)v.w};
  reinterpret_cast<B4s*>(dst)[off] = o;
}

// ---------------- GEMM: C[m][n] = sum_k A[m][k] * W[n][k] ----------------
template <int MODE>
__global__ __launch_bounds__(256) void gemm_kernel(
    const bf16* __restrict__ A,
    const bf16* __restrict__ W0, const bf16* __restrict__ W1, const bf16* __restrict__ W2,
    bf16* __restrict__ q_out, bf16* __restrict__ k_out, bf16* __restrict__ v_out,
    float* __restrict__ c_out) {
  constexpr int BK = 32;
  __shared__ bf16 Alds[128 * BK];
  __shared__ bf16 Blds[128 * BK];
  const int tid = threadIdx.x;
  const int w = tid >> 6, l = tid & 63;
  const int lr = l & 15, lg = l >> 4;
  const int m0 = blockIdx.y * 128;
  const int nt = blockIdx.x;
  const bf16* W;
  int n0;
  if (MODE == 0) {
    W = (nt >> 3) == 0 ? W0 : ((nt >> 3) == 1 ? W1 : W2);
    n0 = (nt & 7) * 128;
  } else {
    W = W0;
    n0 = nt * 128;
  }
  const int K = 1024;
  const int wm = (w >> 1) * 64, wn = (w & 1) * 64;
  const int srow = w * 16 + (l >> 2);
  const int scol = (l & 3) * 8;
  f32x4 acc[4][4] = {};
  for (int k0 = 0; k0 < K; k0 += BK) {
    gload_lds16(A + (size_t)(m0 + srow) * K + k0 + scol, Alds + (w * 16) * BK);
    gload_lds16(A + (size_t)(m0 + 64 + srow) * K + k0 + scol, Alds + (64 + w * 16) * BK);
    gload_lds16(W + (size_t)(n0 + srow) * K + k0 + scol, Blds + (w * 16) * BK);
    gload_lds16(W + (size_t)(n0 + 64 + srow) * K + k0 + scol, Blds + (64 + w * 16) * BK);
    __syncthreads();
    bf16x8 af[4], bfr[4];
#pragma unroll
    for (int f = 0; f < 4; ++f) {
      af[f]  = *reinterpret_cast<const bf16x8*>(Alds + (wm + f * 16 + lr) * BK + lg * 8);
      bfr[f] = *reinterpret_cast<const bf16x8*>(Blds + (wn + f * 16 + lr) * BK + lg * 8);
    }
#pragma unroll
    for (int fm = 0; fm < 4; ++fm)
#pragma unroll
      for (int fn = 0; fn < 4; ++fn)
        acc[fm][fn] = __builtin_amdgcn_mfma_f32_16x16x32_bf16(af[fm], bfr[fn], acc[fm][fn], 0, 0, 0);
    __syncthreads();
  }
#pragma unroll
  for (int fm = 0; fm < 4; ++fm)
#pragma unroll
    for (int fn = 0; fn < 4; ++fn)
#pragma unroll
      for (int r = 0; r < 4; ++r) {
        int m = m0 + wm + fm * 16 + lg * 4 + r;
        int n = n0 + wn + fn * 16 + lr;
        float v = acc[fm][fn][r];
        if (MODE == 0) {
          bf16* dst = (nt >> 3) == 0 ? q_out : ((nt >> 3) == 1 ? k_out : v_out);
          int h = n >> 6, d = n & 63;
          int b = m >> 11, s = m & 2047;
          dst[(((size_t)b * H_ + h) * S_ + s) * DK + d] = (bf16)v;
        } else {
          c_out[(size_t)m * D_ + n] = v;
        }
      }
}

// ---------------- RoPE (vectorized; Q additionally scaled by 1/sqrt(dk)) ----------------
__global__ __launch_bounds__(256) void rope_kernel(bf16* __restrict__ Q, bf16* __restrict__ K) {
  const int NG = 32 * 2048 * 8;  // bf16x8 groups per tensor
  int idx = blockIdx.x * 256 + threadIdx.x;
  bf16* X = Q;
  float sc = 0.125f;
  if (idx >= NG) { X = K; idx -= NG; sc = 1.0f; }
  int g = idx & 7;
  int s = (idx >> 3) & 2047;
  int bh = idx >> 14;
  size_t off = ((size_t)bh * S_ + s) * DK + g * 8;
  bf16x8 v = *reinterpret_cast<const bf16x8*>(X + off);
  bf16x8 o;
  const float c0 = -0.4152410118609203f;  // -log2(10000)/32
  float fs = (float)s;
#pragma unroll
  for (int p = 0; p < 4; ++p) {
    int i = g * 4 + p;
    float ang = fs * exp2f((float)i * c0);
    float sn = __sinf(ang), cs = __cosf(ang);
    float x1 = (float)v[2 * p], x2 = (float)v[2 * p + 1];
    o[2 * p]     = (bf16)((x1 * cs - x2 * sn) * sc);
    o[2 * p + 1] = (bf16)((x1 * sn + x2 * cs) * sc);
  }
  *reinterpret_cast<bf16x8*>(X + off) = o;
}

// ---------------- causal flash attention (paired q-tiles, dbuf prefetch) ----------------
// grid (16, 32): block i handles q-tiles lo=i and hi=31-i of bh=blockIdx.y.
// K staged via pre-swizzled global_load_lds; V staged transposed via reg path (T14 split).
// Double-buffered: next tile's loads issue before current tile's compute.
__global__ __launch_bounds__(256) void attn_kernel(
    const bf16* __restrict__ Q, const bf16* __restrict__ K, const bf16* __restrict__ V,
    bf16* __restrict__ O) {
  __shared__ bf16 Klds[2][64 * 64];
  __shared__ bf16 Vt[2][64 * 64];
  __shared__ bf16 Plds[8][16 * 72];
  const int tid = threadIdx.x;
  const int w = tid >> 6, l = tid & 63;
  const int lr = l & 15, lg = l >> 4;
  const int bh = blockIdx.y;
  const int lo = blockIdx.x, hi = 31 - blockIdx.x;
  const size_t base = (size_t)bh * S_ * DK;

  bf16x8 qfl[2], qfh[2];
  {
    const size_t rl = base + (size_t)(lo * 64 + w * 16 + lr) * DK;
    const size_t rh = base + (size_t)(hi * 64 + w * 16 + lr) * DK;
    qfl[0] = *reinterpret_cast<const bf16x8*>(Q + rl + lg * 8);
    qfl[1] = *reinterpret_cast<const bf16x8*>(Q + rl + 32 + lg * 8);
    qfh[0] = *reinterpret_cast<const bf16x8*>(Q + rh + lg * 8);
    qfh[1] = *reinterpret_cast<const bf16x8*>(Q + rh + 32 + lg * 8);
  }

  float m_lo = -INFINITY, l_lo = 0.f, m_hi = -INFINITY, l_hi = 0.f;
  f32x4 o_lo[4] = {}, o_hi[4] = {};

  const int ksr = l >> 3;
  const int ksc = (l & 7) * 8;

  auto stageK = [&](int kt, int p) {
#pragma unroll
    for (int c2 = 0; c2 < 2; ++c2) {
      int c = w * 2 + c2;
      int row = c * 8 + ksr;
      gload_lds16(K + base + (size_t)(kt * 64 + row) * DK + (ksc ^ ((row & 7) * 8)),
                  &Klds[p][c * 512]);
    }
  };
  auto loadV = [&](int kt, bf16x8& v0, bf16x8& v1) {
    v0 = *reinterpret_cast<const bf16x8*>(V + base + (size_t)(kt * 64 + l) * DK + w * 8);
    v1 = *reinterpret_cast<const bf16x8*>(V + base + (size_t)(kt * 64 + l) * DK + w * 8 + 32);
  };
  auto writeV = [&](int p, const bf16x8& v0, const bf16x8& v1) {
#pragma unroll
    for (int j = 0; j < 8; ++j) {
      Vt[p][(w * 8 + j) * 64 + (l ^ (j * 8))] = v0[j];
      Vt[p][(w * 8 + 32 + j) * 64 + (l ^ (j * 8))] = v1[j];
    }
  };

  auto process = [&](const bf16x8 (&qf)[2], const bf16x8 (&kfr)[4][2],
                     const bf16x8 (&vfr)[4][2], float& m_run, float& l_run,
                     f32x4 (&o_acc)[4], bf16* Pw, bool lastt) {
    f32x4 s[4];
#pragma unroll
    for (int kf = 0; kf < 4; ++kf) {
      f32x4 a = {};
      a = __builtin_amdgcn_mfma_f32_16x16x32_bf16(kfr[kf][0], qf[0], a, 0, 0, 0);
      a = __builtin_amdgcn_mfma_f32_16x16x32_bf16(kfr[kf][1], qf[1], a, 0, 0, 0);
      s[kf] = a;
    }
    float tmax = -INFINITY;
#pragma unroll
    for (int kf = 0; kf < 4; ++kf)
#pragma unroll
      for (int r = 0; r < 4; ++r) {
        float v = s[kf][r];
        if (lastt) {
          if (kf * 16 + 4 * lg + r > w * 16 + lr) v = -INFINITY;
        }
        s[kf][r] = v;
        tmax = fmaxf(tmax, v);
      }
    tmax = fmaxf(tmax, __shfl_xor(tmax, 16));
    tmax = fmaxf(tmax, __shfl_xor(tmax, 32));
    float m_new = fmaxf(m_run, tmax);
    float sf = __expf(m_run - m_new);
    float ts = 0.f;
#pragma unroll
    for (int kf = 0; kf < 4; ++kf)
#pragma unroll
      for (int r = 0; r < 4; ++r) {
        float p = __expf(s[kf][r] - m_new);
        s[kf][r] = p;
        ts += p;
      }
    ts += __shfl_xor(ts, 16);
    ts += __shfl_xor(ts, 32);
    l_run = l_run * sf + ts;
    m_run = m_new;
#pragma unroll
    for (int kf = 0; kf < 4; ++kf) {
      B4s p4{(bf16)s[kf][0], (bf16)s[kf][1], (bf16)s[kf][2], (bf16)s[kf][3]};
      *reinterpret_cast<B4s*>(Pw + lr * 72 + kf * 16 + 4 * lg) = p4;
    }
    float sfr0 = __shfl(sf, 4 * lg + 0);
    float sfr1 = __shfl(sf, 4 * lg + 1);
    float sfr2 = __shfl(sf, 4 * lg + 2);
    float sfr3 = __shfl(sf, 4 * lg + 3);
#pragma unroll
    for (int dt = 0; dt < 4; ++dt) {
      o_acc[dt][0] *= sfr0; o_acc[dt][1] *= sfr1;
      o_acc[dt][2] *= sfr2; o_acc[dt][3] *= sfr3;
    }
    bf16x8 pa0 = *reinterpret_cast<const bf16x8*>(Pw + lr * 72 + lg * 8);
    bf16x8 pa1 = *reinterpret_cast<const bf16x8*>(Pw + lr * 72 + 32 + lg * 8);
#pragma unroll
    for (int dt = 0; dt < 4; ++dt) {
      o_acc[dt] = __builtin_amdgcn_mfma_f32_16x16x32_bf16(pa0, vfr[dt][0], o_acc[dt], 0, 0, 0);
      o_acc[dt] = __builtin_amdgcn_mfma_f32_16x16x32_bf16(pa1, vfr[dt][1], o_acc[dt], 0, 0, 0);
    }
  };

  // prologue: stage tile 0
  {
    stageK(0, 0);
    bf16x8 v0, v1;
    loadV(0, v0, v1);
    writeV(0, v0, v1);
  }
  __syncthreads();  // compiler drains vmcnt+lgkm before barrier

  bf16x8 pv0, pv1;
  for (int kt = 0; kt <= hi; ++kt) {
    const int p = kt & 1;
    const bool pre = kt < hi;
    if (pre) {
      stageK(kt + 1, p ^ 1);   // async global->LDS, drained by end-of-iter barrier
      loadV(kt + 1, pv0, pv1); // global->reg, waited at writeV below
    }
    // fragments for current tile (shared by hi and lo)
    bf16x8 kfr[4][2], vfr[4][2];
#pragma unroll
    for (int kf = 0; kf < 4; ++kf) {
      int key = kf * 16 + lr;
#pragma unroll
      for (int kk = 0; kk < 2; ++kk)
        kfr[kf][kk] = *reinterpret_cast<const bf16x8*>(
            &Klds[p][key * 64 + ((kk * 32 + lg * 8) ^ ((key & 7) * 8))]);
    }
#pragma unroll
    for (int dt = 0; dt < 4; ++dt) {
      int d = dt * 16 + lr;
      int sw = (d & 7) * 8;
      vfr[dt][0] = *reinterpret_cast<const bf16x8*>(&Vt[p][d * 64 + ((lg * 8) ^ sw)]);
      vfr[dt][1] = *reinterpret_cast<const bf16x8*>(&Vt[p][d * 64 + ((32 + lg * 8) ^ sw)]);
    }

    process(qfh, kfr, vfr, m_hi, l_hi, o_hi, Plds[w], kt == hi);
    if (kt <= lo)
      process(qfl, kfr, vfr, m_lo, l_lo, o_lo, Plds[w + 4], kt == lo);

    if (pre) writeV(p ^ 1, pv0, pv1);
    __syncthreads();
  }

  const int b = bh >> 4, h = bh & 15;
  auto epi = [&](float l_run, f32x4 (&o_acc)[4], int q0t) {
    float inv = 1.0f / l_run;
    float ir[4];
    ir[0] = __shfl(inv, 4 * lg + 0);
    ir[1] = __shfl(inv, 4 * lg + 1);
    ir[2] = __shfl(inv, 4 * lg + 2);
    ir[3] = __shfl(inv, 4 * lg + 3);
#pragma unroll
    for (int dt = 0; dt < 4; ++dt)
#pragma unroll
      for (int r = 0; r < 4; ++r) {
        int qrow = q0t + w * 16 + 4 * lg + r;
        int n = h * DK + dt * 16 + lr;
        O[((size_t)b * S_ + qrow) * D_ + n] = (bf16)(o_acc[dt][r] * ir[r]);
      }
  };
  epi(l_hi, o_hi, hi * 64);
  epi(l_lo, o_lo, lo * 64);
}

extern "C" void kernel_launch(void* const* d_in, const int* in_sizes, int n_in,
                              void* d_out, int out_size, void* d_ws, size_t ws_size,
                              hipStream_t stream) {
  const float* x  = (const float*)d_in[0];
  const float* Wq = (const float*)d_in[1];
  const float* Wk = (const float*)d_in[2];
  const float* Wv = (const float*)d_in[3];
  const float* Wo = (const float*)d_in[4];
  float* out = (float*)d_out;
  char* ws = (char*)d_ws;

  bf16* xb  = (bf16*)(ws + ((size_t)0 << 20));
  bf16* wqb = (bf16*)(ws + ((size_t)8 << 20));
  bf16* wkb = (bf16*)(ws + ((size_t)10 << 20));
  bf16* wvb = (bf16*)(ws + ((size_t)12 << 20));
  bf16* wob = (bf16*)(ws + ((size_t)14 << 20));
  bf16* Qb  = (bf16*)(ws + ((size_t)16 << 20));
  bf16* Kb  = (bf16*)(ws + ((size_t)24 << 20));
  bf16* Vb  = (bf16*)(ws + ((size_t)32 << 20));
  bf16* Ob  = (bf16*)(ws + ((size_t)40 << 20));

  cvt_all_kernel<<<8192, 256, 0, stream>>>(x, Wq, Wk, Wv, Wo, xb, wqb, wkb, wvb, wob);
  gemm_kernel<0><<<dim3(24, 32), 256, 0, stream>>>(xb, wqb, wkb, wvb, Qb, Kb, Vb, nullptr);
  rope_kernel<<<4096, 256, 0, stream>>>(Qb, Kb);
  attn_kernel<<<dim3(16, 32), 256, 0, stream>>>(Qb, Kb, Vb, Ob);
  gemm_kernel<1><<<dim3(8, 32), 256, 0, stream>>>(Ob, wob, nullptr, nullptr, nullptr, nullptr,
                                                  nullptr, out);
}

// Round 5
// 127.265 us; speedup vs baseline: 2.4210x; 1.0538x over previous
//
#include <hip/hip_runtime.h>
#include <hip/hip_bf16.h>
#include <stdint.h>

typedef __bf16 bf16;
typedef __bf16 bf16x8 __attribute__((ext_vector_type(8)));
typedef float f32x4 __attribute__((ext_vector_type(4)));

#define B_ 2
#define S_ 2048
#define D_ 1024
#define H_ 16
#define DK 64
#define M_ 4096

__device__ __forceinline__ void gload_lds16(const void* g, void* l) {
  __builtin_amdgcn_global_load_lds(
      (const __attribute__((address_space(1))) uint32_t*)(uintptr_t)g,
      (__attribute__((address_space(3))) uint32_t*)(uintptr_t)l, 16, 0, 0);
}

// ---------------- f32 -> bf16 convert (all 5 tensors, one launch) ----------------
struct alignas(8) B4s { bf16 a, b, c, d; };

__global__ __launch_bounds__(256) void cvt_all_kernel(
    const float* __restrict__ x, const float* __restrict__ wq, const float* __restrict__ wk,
    const float* __restrict__ wv, const float* __restrict__ wo,
    bf16* __restrict__ xb, bf16* __restrict__ wqb, bf16* __restrict__ wkb,
    bf16* __restrict__ wvb, bf16* __restrict__ wob) {
  int i = blockIdx.x * 256 + threadIdx.x;  // float4 index
  const float* src;
  bf16* dst;
  int off;
  if (i < 1048576) { src = x; dst = xb; off = i; }
  else if (i < 1310720) { src = wq; dst = wqb; off = i - 1048576; }
  else if (i < 1572864) { src = wk; dst = wkb; off = i - 1310720; }
  else if (i < 1835008) { src = wv; dst = wvb; off = i - 1572864; }
  else { src = wo; dst = wob; off = i - 1835008; }
  float4 v = reinterpret_cast<const float4*>(src)[off];
  B4s o{(bf16)v.x, (bf16)v.y, (bf16)v.z, (bf16)v.w};
  reinterpret_cast<B4s*>(dst)[off] = o;
}

// ---------------- GEMM: C[m][n] = sum_k A[m][k] * W[n][k] ----------------
template <int MODE>
__global__ __launch_bounds__(256) void gemm_kernel(
    const bf16* __restrict__ A,
    const bf16* __restrict__ W0, const bf16* __restrict__ W1, const bf16* __restrict__ W2,
    bf16* __restrict__ q_out, bf16* __restrict__ k_out, bf16* __restrict__ v_out,
    float* __restrict__ c_out) {
  constexpr int BK = 32;
  __shared__ bf16 Alds[128 * BK];
  __shared__ bf16 Blds[128 * BK];
  const int tid = threadIdx.x;
  const int w = tid >> 6, l = tid & 63;
  const int lr = l & 15, lg = l >> 4;
  const int m0 = blockIdx.y * 128;
  const int nt = blockIdx.x;
  const bf16* W;
  int n0;
  if (MODE == 0) {
    W = (nt >> 3) == 0 ? W0 : ((nt >> 3) == 1 ? W1 : W2);
    n0 = (nt & 7) * 128;
  } else {
    W = W0;
    n0 = nt * 128;
  }
  const int K = 1024;
  const int wm = (w >> 1) * 64, wn = (w & 1) * 64;
  const int srow = w * 16 + (l >> 2);
  const int scol = (l & 3) * 8;
  f32x4 acc[4][4] = {};
  for (int k0 = 0; k0 < K; k0 += BK) {
    gload_lds16(A + (size_t)(m0 + srow) * K + k0 + scol, Alds + (w * 16) * BK);
    gload_lds16(A + (size_t)(m0 + 64 + srow) * K + k0 + scol, Alds + (64 + w * 16) * BK);
    gload_lds16(W + (size_t)(n0 + srow) * K + k0 + scol, Blds + (w * 16) * BK);
    gload_lds16(W + (size_t)(n0 + 64 + srow) * K + k0 + scol, Blds + (64 + w * 16) * BK);
    __syncthreads();
    bf16x8 af[4], bfr[4];
#pragma unroll
    for (int f = 0; f < 4; ++f) {
      af[f]  = *reinterpret_cast<const bf16x8*>(Alds + (wm + f * 16 + lr) * BK + lg * 8);
      bfr[f] = *reinterpret_cast<const bf16x8*>(Blds + (wn + f * 16 + lr) * BK + lg * 8);
    }
#pragma unroll
    for (int fm = 0; fm < 4; ++fm)
#pragma unroll
      for (int fn = 0; fn < 4; ++fn)
        acc[fm][fn] = __builtin_amdgcn_mfma_f32_16x16x32_bf16(af[fm], bfr[fn], acc[fm][fn], 0, 0, 0);
    __syncthreads();
  }
#pragma unroll
  for (int fm = 0; fm < 4; ++fm)
#pragma unroll
    for (int fn = 0; fn < 4; ++fn)
#pragma unroll
      for (int r = 0; r < 4; ++r) {
        int m = m0 + wm + fm * 16 + lg * 4 + r;
        int n = n0 + wn + fn * 16 + lr;
        float v = acc[fm][fn][r];
        if (MODE == 0) {
          bf16* dst = (nt >> 3) == 0 ? q_out : ((nt >> 3) == 1 ? k_out : v_out);
          int h = n >> 6, d = n & 63;
          int b = m >> 11, s = m & 2047;
          dst[(((size_t)b * H_ + h) * S_ + s) * DK + d] = (bf16)v;
        } else {
          c_out[(size_t)m * D_ + n] = v;
        }
      }
}

// ---------------- RoPE (vectorized; Q scaled by log2(e)/sqrt(dk) for exp2 softmax) -------
__global__ __launch_bounds__(256) void rope_kernel(bf16* __restrict__ Q, bf16* __restrict__ K) {
  const int NG = 32 * 2048 * 8;  // bf16x8 groups per tensor
  int idx = blockIdx.x * 256 + threadIdx.x;
  bf16* X = Q;
  float sc = 0.18033688f;  // 0.125 * log2(e)
  if (idx >= NG) { X = K; idx -= NG; sc = 1.0f; }
  int g = idx & 7;
  int s = (idx >> 3) & 2047;
  int bh = idx >> 14;
  size_t off = ((size_t)bh * S_ + s) * DK + g * 8;
  bf16x8 v = *reinterpret_cast<const bf16x8*>(X + off);
  bf16x8 o;
  const float c0 = -0.4152410118609203f;  // -log2(10000)/32
  float fs = (float)s;
#pragma unroll
  for (int p = 0; p < 4; ++p) {
    int i = g * 4 + p;
    float ang = fs * exp2f((float)i * c0);
    float sn = __sinf(ang), cs = __cosf(ang);
    float x1 = (float)v[2 * p], x2 = (float)v[2 * p + 1];
    o[2 * p]     = (bf16)((x1 * cs - x2 * sn) * sc);
    o[2 * p + 1] = (bf16)((x1 * sn + x2 * cs) * sc);
  }
  *reinterpret_cast<bf16x8*>(X + off) = o;
}

// ---------------- causal flash attention (single q-tile blocks, longest-first) ----------
// grid 1024: block handles q-tile qt = 31 - bid/32 of bh = bid%32 (long tiles launch first;
// all 1024 blocks co-resident at 4/CU). Scores arrive in log2 domain (Q pre-scaled).
// K double-buffered via pre-swizzled global_load_lds; V single-buffered reg-staged (T14);
// defer-max (T13, THR=11 in log2): rescale only when running max grows materially.
__global__ __launch_bounds__(256, 4) void attn_kernel(
    const bf16* __restrict__ Q, const bf16* __restrict__ K, const bf16* __restrict__ V,
    bf16* __restrict__ O) {
  __shared__ bf16 Klds[2][64 * 64];
  __shared__ bf16 Vt[64 * 64];
  __shared__ bf16 Plds[4][16 * 72];
  const int tid = threadIdx.x;
  const int w = tid >> 6, l = tid & 63;
  const int lr = l & 15, lg = l >> 4;
  const int qt = 31 - (int)(blockIdx.x >> 5);
  const int bh = blockIdx.x & 31;
  const size_t base = (size_t)bh * S_ * DK;

  const size_t qoff = base + (size_t)(qt * 64 + w * 16 + lr) * DK;
  bf16x8 qf0 = *reinterpret_cast<const bf16x8*>(Q + qoff + lg * 8);
  bf16x8 qf1 = *reinterpret_cast<const bf16x8*>(Q + qoff + 32 + lg * 8);

  float m_run = -INFINITY, l_run = 0.f;
  f32x4 o_acc[4] = {};
  bf16* Pw = Plds[w];

  const int ksr = l >> 3;
  const int ksc = (l & 7) * 8;

  auto stageK = [&](int kt, int p) {
#pragma unroll
    for (int c2 = 0; c2 < 2; ++c2) {
      int c = w * 2 + c2;
      int row = c * 8 + ksr;
      gload_lds16(K + base + (size_t)(kt * 64 + row) * DK + (ksc ^ ((row & 7) * 8)),
                  &Klds[p][c * 512]);
    }
  };
  auto loadV = [&](int kt, bf16x8& v0, bf16x8& v1) {
    v0 = *reinterpret_cast<const bf16x8*>(V + base + (size_t)(kt * 64 + l) * DK + w * 8);
    v1 = *reinterpret_cast<const bf16x8*>(V + base + (size_t)(kt * 64 + l) * DK + w * 8 + 32);
  };
  auto writeV = [&](const bf16x8& v0, const bf16x8& v1) {
#pragma unroll
    for (int j = 0; j < 8; ++j) {
      Vt[(w * 8 + j) * 64 + (l ^ (j * 8))] = v0[j];
      Vt[(w * 8 + 32 + j) * 64 + (l ^ (j * 8))] = v1[j];
    }
  };

  // prologue: stage tile 0
  {
    stageK(0, 0);
    bf16x8 v0, v1;
    loadV(0, v0, v1);
    writeV(v0, v1);
  }
  __syncthreads();

  bf16x8 pv0, pv1;
  for (int kt = 0; kt <= qt; ++kt) {
    const int p = kt & 1;
    const bool pre = kt < qt;
    if (pre) {
      stageK(kt + 1, p ^ 1);   // async global->LDS; drained at the post-compute barrier
      loadV(kt + 1, pv0, pv1); // global->reg; consumed after that barrier
    }
    // --- QK^T ---
    f32x4 s[4];
#pragma unroll
    for (int kf = 0; kf < 4; ++kf) {
      int key = kf * 16 + lr;
      bf16x8 k0 = *reinterpret_cast<const bf16x8*>(
          &Klds[p][key * 64 + ((lg * 8) ^ ((key & 7) * 8))]);
      bf16x8 k1 = *reinterpret_cast<const bf16x8*>(
          &Klds[p][key * 64 + ((32 + lg * 8) ^ ((key & 7) * 8))]);
      f32x4 a = {};
      a = __builtin_amdgcn_mfma_f32_16x16x32_bf16(k0, qf0, a, 0, 0, 0);
      a = __builtin_amdgcn_mfma_f32_16x16x32_bf16(k1, qf1, a, 0, 0, 0);
      s[kf] = a;
    }
    // --- mask + max ---
    float tmax = -INFINITY;
    const bool lastt = (kt == qt);
#pragma unroll
    for (int kf = 0; kf < 4; ++kf)
#pragma unroll
      for (int r = 0; r < 4; ++r) {
        float v = s[kf][r];
        if (lastt && (kf * 16 + 4 * lg + r > w * 16 + lr)) v = -INFINITY;
        s[kf][r] = v;
        tmax = fmaxf(tmax, v);
      }
    tmax = fmaxf(tmax, __shfl_xor(tmax, 16));
    tmax = fmaxf(tmax, __shfl_xor(tmax, 32));
    // --- defer-max: rescale only if max grew materially (log2 units) ---
    if (!__all(tmax <= m_run + 11.0f)) {
      float m_new = fmaxf(m_run, tmax);
      float sf = exp2f(m_run - m_new);
      l_run *= sf;
      float sfr0 = __shfl(sf, 4 * lg + 0);
      float sfr1 = __shfl(sf, 4 * lg + 1);
      float sfr2 = __shfl(sf, 4 * lg + 2);
      float sfr3 = __shfl(sf, 4 * lg + 3);
#pragma unroll
      for (int dt = 0; dt < 4; ++dt) {
        o_acc[dt][0] *= sfr0; o_acc[dt][1] *= sfr1;
        o_acc[dt][2] *= sfr2; o_acc[dt][3] *= sfr3;
      }
      m_run = m_new;
    }
    // --- exp2 + sum ---
    float ts = 0.f;
#pragma unroll
    for (int kf = 0; kf < 4; ++kf)
#pragma unroll
      for (int r = 0; r < 4; ++r) {
        float pp = exp2f(s[kf][r] - m_run);
        s[kf][r] = pp;
        ts += pp;
      }
    ts += __shfl_xor(ts, 16);
    ts += __shfl_xor(ts, 32);
    l_run += ts;
    // --- P roundtrip (per-wave LDS, padded stride 72) ---
#pragma unroll
    for (int kf = 0; kf < 4; ++kf) {
      B4s p4{(bf16)s[kf][0], (bf16)s[kf][1], (bf16)s[kf][2], (bf16)s[kf][3]};
      *reinterpret_cast<B4s*>(Pw + lr * 72 + kf * 16 + 4 * lg) = p4;
    }
    bf16x8 pa0 = *reinterpret_cast<const bf16x8*>(Pw + lr * 72 + lg * 8);
    bf16x8 pa1 = *reinterpret_cast<const bf16x8*>(Pw + lr * 72 + 32 + lg * 8);
    // --- PV ---
#pragma unroll
    for (int dt = 0; dt < 4; ++dt) {
      int d = dt * 16 + lr;
      int sw = (d & 7) * 8;
      bf16x8 v0 = *reinterpret_cast<const bf16x8*>(&Vt[d * 64 + ((lg * 8) ^ sw)]);
      bf16x8 v1 = *reinterpret_cast<const bf16x8*>(&Vt[d * 64 + ((32 + lg * 8) ^ sw)]);
      o_acc[dt] = __builtin_amdgcn_mfma_f32_16x16x32_bf16(pa0, v0, o_acc[dt], 0, 0, 0);
      o_acc[dt] = __builtin_amdgcn_mfma_f32_16x16x32_bf16(pa1, v1, o_acc[dt], 0, 0, 0);
    }
    __syncthreads();            // all waves done reading Vt; prefetch drains here
    if (pre) writeV(pv0, pv1);  // fill Vt for next tile
    __syncthreads();
  }

  const int b = bh >> 4, h = bh & 15;
  float inv = 1.0f / l_run;
  float ir[4];
  ir[0] = __shfl(inv, 4 * lg + 0);
  ir[1] = __shfl(inv, 4 * lg + 1);
  ir[2] = __shfl(inv, 4 * lg + 2);
  ir[3] = __shfl(inv, 4 * lg + 3);
#pragma unroll
  for (int dt = 0; dt < 4; ++dt)
#pragma unroll
    for (int r = 0; r < 4; ++r) {
      int qrow = qt * 64 + w * 16 + 4 * lg + r;
      int n = h * DK + dt * 16 + lr;
      O[((size_t)b * S_ + qrow) * D_ + n] = (bf16)(o_acc[dt][r] * ir[r]);
    }
}

extern "C" void kernel_launch(void* const* d_in, const int* in_sizes, int n_in,
                              void* d_out, int out_size, void* d_ws, size_t ws_size,
                              hipStream_t stream) {
  const float* x  = (const float*)d_in[0];
  const float* Wq = (const float*)d_in[1];
  const float* Wk = (const float*)d_in[2];
  const float* Wv = (const float*)d_in[3];
  const float* Wo = (const float*)d_in[4];
  float* out = (float*)d_out;
  char* ws = (char*)d_ws;

  bf16* xb  = (bf16*)(ws + ((size_t)0 << 20));
  bf16* wqb = (bf16*)(ws + ((size_t)8 << 20));
  bf16* wkb = (bf16*)(ws + ((size_t)10 << 20));
  bf16* wvb = (bf16*)(ws + ((size_t)12 << 20));
  bf16* wob = (bf16*)(ws + ((size_t)14 << 20));
  bf16* Qb  = (bf16*)(ws + ((size_t)16 << 20));
  bf16* Kb  = (bf16*)(ws + ((size_t)24 << 20));
  bf16* Vb  = (bf16*)(ws + ((size_t)32 << 20));
  bf16* Ob  = (bf16*)(ws + ((size_t)40 << 20));

  cvt_all_kernel<<<8192, 256, 0, stream>>>(x, Wq, Wk, Wv, Wo, xb, wqb, wkb, wvb, wob);
  gemm_kernel<0><<<dim3(24, 32), 256, 0, stream>>>(xb, wqb, wkb, wvb, Qb, Kb, Vb, nullptr);
  rope_kernel<<<4096, 256, 0, stream>>>(Qb, Kb);
  attn_kernel<<<1024, 256, 0, stream>>>(Qb, Kb, Vb, Ob);
  gemm_kernel<1><<<dim3(8, 32), 256, 0, stream>>>(Ob, wob, nullptr, nullptr, nullptr, nullptr,
                                                  nullptr, out);
}